// Round 1
// baseline (4257.097 us; speedup 1.0000x reference)
//
#include <hip/hip_runtime.h>
#include <stdint.h>
#include <initializer_list>

typedef unsigned short u16;
typedef __bf16 bf16x8 __attribute__((ext_vector_type(8)));
typedef float f32x4 __attribute__((ext_vector_type(4)));

static constexpr int NB  = 256;   // batch
static constexpr int NH  = 2048;  // H
static constexpr int NF  = 1024;  // F
static constexpr int NZ  = 512;   // Z
static constexpr int NT  = 16;    // T
static constexpr int NTS = 32;    // TS
static constexpr int NG4 = 8192;  // 4*H
static constexpr int NDK = 3584;  // H+F+Z

// ---------- helpers ----------
__device__ __forceinline__ u16 f2bf(float f) {
  union { float f; uint32_t u; } x; x.f = f;
  uint32_t r = x.u + 0x7fffu + ((x.u >> 16) & 1u);
  return (u16)(r >> 16);
}
__device__ __forceinline__ float sigm(float x) { return 1.f / (1.f + expf(-x)); }

__device__ __forceinline__ void gload16(const void* g, void* l) {
  __builtin_amdgcn_global_load_lds(
      (__attribute__((address_space(1))) void*)const_cast<void*>(g),
      (__attribute__((address_space(3))) void*)l, 16, 0, 0);
}

// ---------- weight transpose + cast:  WT[n*K + k] = bf16(W[k*N + n]) ----------
__global__ __launch_bounds__(256) void transpose_cast(const float* __restrict__ W,
                                                      u16* __restrict__ WT,
                                                      int K, int N) {
  __shared__ float tile[32][33];
  const int k0 = blockIdx.x * 32, n0 = blockIdx.y * 32;
  const int t = threadIdx.x;
  const int r = t >> 3, cg = t & 7;
  const float4 v = *(const float4*)(W + (size_t)(k0 + r) * N + n0 + cg * 4);
  tile[r][cg * 4 + 0] = v.x; tile[r][cg * 4 + 1] = v.y;
  tile[r][cg * 4 + 2] = v.z; tile[r][cg * 4 + 3] = v.w;
  __syncthreads();
  ushort4 o;
  o.x = f2bf(tile[cg * 4 + 0][r]);
  o.y = f2bf(tile[cg * 4 + 1][r]);
  o.z = f2bf(tile[cg * 4 + 2][r]);
  o.w = f2bf(tile[cg * 4 + 3][r]);
  *(ushort4*)(WT + (size_t)(n0 + r) * K + k0 + cg * 4) = o;
}

__global__ __launch_bounds__(256) void cast_f32_bf16(const float* __restrict__ src,
                                                     u16* __restrict__ dst, int n) {
  int i = (blockIdx.x * 256 + threadIdx.x) * 4;
  if (i < n) {
    float4 v = *(const float4*)(src + i);
    ushort4 o; o.x = f2bf(v.x); o.y = f2bf(v.y); o.z = f2bf(v.z); o.w = f2bf(v.w);
    *(ushort4*)(dst + i) = o;
  }
}

__global__ __launch_bounds__(256) void build_bias(const float* b5, const float* b6, float* b56,
                                                  const float* b8, const float* b9, float* b89) {
  int i = blockIdx.x * 256 + threadIdx.x;
  if (i < 1024) {
    b56[i] = (i < 512) ? b5[i] : b6[i - 512];
    b89[i] = (i < 512) ? b8[i] : b9[i - 512];
  }
}

// ---------- time / lam precompute (fp32 exact) ----------
__global__ __launch_bounds__(256) void time_k(const float* __restrict__ input_t,
                                              const float* alpha, const float* beta,
                                              const float* base_, const float* tw,
                                              float* __restrict__ lam_buf,
                                              float* __restrict__ out_it,
                                              float* __restrict__ out_te) {
  int i = blockIdx.x * 256 + threadIdx.x;       // NB*NT
  int b = i >> 4, j = i & 15;
  const float* row = input_t + b * NTS;
  float cur = row[16 + j];
  float trig = 0.f;
  int lim = 16 + j;
  for (int s = 0; s < lim; ++s) trig += expf(row[s] - cur);
  float lam = base_[0] + alpha[0] * beta[0] * trig;
  float x = lam * (2048.f * tw[0]);
  float dt = (x > 15.f) ? x : log1pf(expf(x));
  lam_buf[b * NT + j] = lam;
  out_it[j * NB + b] = cur;
  out_te[j * NB + b] = cur + dt;
}

// ---------- LSTM cell ----------
__global__ __launch_bounds__(256) void cell_k(const float* __restrict__ gates,
                                              const float* __restrict__ lam, int t,
                                              float* __restrict__ c,
                                              u16* __restrict__ s_bf,
                                              u16* __restrict__ h_bf) {
  int i = blockIdx.x * 256 + threadIdx.x;       // NB*NH
  int b = i >> 11, n = i & 2047;
  const float* gr = gates + (size_t)b * NG4;
  float ig = gr[n], fg = gr[n + 2048], gg = gr[n + 4096], og = gr[n + 6144];
  float c_new = sigm(fg) * c[i] + sigm(ig) * tanhf(gg);
  float h_new = sigm(og) * tanhf(c_new);
  c[i] = lam[b * NT + t] * c_new;
  s_bf[i] = f2bf(c_new);
  h_bf[i] = f2bf(h_new);
}

// ---------- z sampling ----------
__global__ __launch_bounds__(256) void z_k(const float* __restrict__ means,
                                           const float* __restrict__ logvs,
                                           const float* __restrict__ noise, int t,
                                           float* __restrict__ zs, u16* __restrict__ z_bf) {
  int i = blockIdx.x * 256 + threadIdx.x;       // NB*NZ
  int b = i >> 9, n = i & 511;
  size_t oidx = ((size_t)b * NT + t) * NZ + n;
  float zv = fmaf(noise[(size_t)t * NB * NZ + i], sqrtf(expf(logvs[oidx])), means[oidx]);
  zs[oidx] = zv;
  z_bf[i] = f2bf(zv);
}

__global__ __launch_bounds__(256) void zp_k(const float* __restrict__ mp,
                                            const float* __restrict__ lp,
                                            const float* __restrict__ noise, int t,
                                            float* __restrict__ zps) {
  int i = blockIdx.x * 256 + threadIdx.x;       // NB*NZ
  int b = i >> 9, n = i & 511;
  float zv = fmaf(noise[(size_t)t * NB * NZ + i], sqrtf(expf(lp[i])), mp[i]);
  zps[((size_t)b * NT + t) * NZ + n] = zv;
}

// ---------- multi-source bf16 MFMA GEMM ----------
// C[m][n] = act( init[m][n] + bias[n] + sum_s A_s[m][:] . WT_s[n][:] )
// A_s: (256, K_s) bf16 row-major (lda = K_s); WT_s: row n holds W[:,n] (k-contig).
struct SrcDesc { const u16* A; const u16* W; int ldw; int K; };
struct GemmArgs {
  SrcDesc src[3];
  int nsrc, N, relu, nsplit;
  const float* C0;     // (256,N) fp32 or null
  const float* bias;   // (N) or null
  float* outf0; float* outf1;
  u16* outbf;
  int os0, os1, osb;
};

__global__ __launch_bounds__(256) void gemm_ms(GemmArgs g) {
  __shared__ __attribute__((aligned(16))) u16 As[64 * 32];
  __shared__ __attribute__((aligned(16))) u16 Ws[64 * 32];
  const int tid = threadIdx.x;
  const int wave = tid >> 6, lane = tid & 63;
  const int m0 = blockIdx.x * 64;
  const int n0 = blockIdx.y * 64;
  f32x4 acc[4] = {};
  const int srow = tid >> 2;            // staging row 0..63
  const int schunk = (tid & 3) * 8;     // staging 8-elem chunk
  const int rb = (lane & 15) * 32 + (lane >> 4) * 8;   // frag read offset

  for (int s = 0; s < g.nsrc; ++s) {
    const u16* A = g.src[s].A;
    const u16* W = g.src[s].W;
    const int K = g.src[s].K, ldw = g.src[s].ldw;
    const u16* ga = A + (size_t)(m0 + srow) * K + schunk;
    const u16* gw = W + (size_t)(n0 + srow) * ldw + schunk;
    for (int k0 = 0; k0 < K; k0 += 32) {
      __syncthreads();                  // prior reads done before overwrite
      gload16(ga + k0, &As[tid * 8]);
      gload16(gw + k0, &Ws[tid * 8]);
      __syncthreads();                  // staging complete
      bf16x8 av = *(const bf16x8*)(&As[wave * 512 + rb]);
#pragma unroll
      for (int fn = 0; fn < 4; ++fn) {
        bf16x8 bv = *(const bf16x8*)(&Ws[fn * 512 + rb]);
        acc[fn] = __builtin_amdgcn_mfma_f32_16x16x32_bf16(av, bv, acc[fn], 0, 0, 0);
      }
    }
  }

  const int cl = lane & 15;
  const int rl = (lane >> 4) * 4;
  const int mb = m0 + wave * 16 + rl;
#pragma unroll
  for (int fn = 0; fn < 4; ++fn) {
    const int n = n0 + fn * 16 + cl;
    const float bv = g.bias ? g.bias[n] : 0.f;
#pragma unroll
    for (int r = 0; r < 4; ++r) {
      const int m = mb + r;
      float v = acc[fn][r] + bv;
      if (g.C0) v += g.C0[(size_t)m * g.N + n];
      if (g.relu) v = fmaxf(v, 0.f);
      if (g.outf0) {
        if (n < g.nsplit) g.outf0[(size_t)m * g.os0 + n] = v;
        else              g.outf1[(size_t)m * g.os1 + (n - g.nsplit)] = v;
      }
      if (g.outbf) g.outbf[(size_t)m * g.osb + n] = f2bf(v);
    }
  }
}

// ---------- launcher ----------
extern "C" void kernel_launch(void* const* d_in, const int* in_sizes, int n_in,
                              void* d_out, int out_size, void* d_ws, size_t ws_size,
                              hipStream_t stream) {
  const float* h_i  = (const float*)d_in[0];
  const float* in_t = (const float*)d_in[1];
  const float* Wk   = (const float*)d_in[2];
  const float* Wr   = (const float*)d_in[3];
  const float* bl   = (const float*)d_in[4];
  const float* W1 = (const float*)d_in[5];  const float* b1 = (const float*)d_in[6];
  const float* W2 = (const float*)d_in[7];  const float* b2 = (const float*)d_in[8];
  const float* W3 = (const float*)d_in[9];  const float* b3 = (const float*)d_in[10];
  const float* W4 = (const float*)d_in[11]; const float* b4 = (const float*)d_in[12];
  const float* W5 = (const float*)d_in[13]; const float* b5 = (const float*)d_in[14];
  const float* W6 = (const float*)d_in[15]; const float* b6 = (const float*)d_in[16];
  const float* W7 = (const float*)d_in[17]; const float* b7 = (const float*)d_in[18];
  const float* W8 = (const float*)d_in[19]; const float* b8 = (const float*)d_in[20];
  const float* W9 = (const float*)d_in[21]; const float* b9 = (const float*)d_in[22];
  const float* alpha = (const float*)d_in[23];
  const float* beta  = (const float*)d_in[24];
  const float* base_ = (const float*)d_in[25];
  const float* tw    = (const float*)d_in[26];
  const float* ninf  = (const float*)d_in[27];
  const float* npri  = (const float*)d_in[28];
  float* out = (float*)d_out;

  // ---- workspace layout (total ~142 MB) ----
  char* wsb = (char*)d_ws;
  size_t off = 0;
  auto alloc = [&](size_t bytes) -> void* {
    void* p = wsb + off;
    off += (bytes + 255) & ~(size_t)255;
    return p;
  };
  u16* WkT  = (u16*)alloc((size_t)NG4 * NDK * 2);
  u16* WrT  = (u16*)alloc((size_t)NG4 * NH * 2);
  u16* W1T  = (u16*)alloc((size_t)NF * NH * 2);
  u16* W2T  = (u16*)alloc((size_t)NF * NF * 2);
  u16* W3T  = (u16*)alloc((size_t)NF * NF * 2);
  u16* W4T  = (u16*)alloc((size_t)NZ * 6144 * 2);
  u16* W56T = (u16*)alloc((size_t)1024 * NZ * 2);
  u16* W7T  = (u16*)alloc((size_t)NZ * 5120 * 2);
  u16* W89T = (u16*)alloc((size_t)1024 * NZ * 2);
  u16* hi_bf = (u16*)alloc((size_t)NB * NH * 2);
  float* b56 = (float*)alloc(1024 * 4);
  float* b89 = (float*)alloc(1024 * 4);
  float* Gc  = (float*)alloc((size_t)NB * NG4 * 4);
  float* H4c = (float*)alloc((size_t)NB * NZ * 4);
  float* H7c = (float*)alloc((size_t)NB * NZ * 4);
  float* gates = (float*)alloc((size_t)NB * NG4 * 4);
  float* lam = (float*)alloc((size_t)NB * NT * 4);
  float* mp  = (float*)alloc((size_t)NB * NZ * 4);
  float* lp  = (float*)alloc((size_t)NB * NZ * 4);
  char* zero_start = wsb + off;
  u16* z0  = (u16*)alloc((size_t)NB * NZ * 2);
  u16* y0  = (u16*)alloc((size_t)NB * NF * 2);
  u16* hbf = (u16*)alloc((size_t)NB * NH * 2);
  float* c = (float*)alloc((size_t)NB * NH * 4);
  size_t zero_bytes = (size_t)((wsb + off) - zero_start);
  u16* z1    = (u16*)alloc((size_t)NB * NZ * 2);
  u16* y1alt = (u16*)alloc((size_t)NB * NF * 2);
  u16* y1_bf = (u16*)alloc((size_t)NB * NF * 2);
  u16* y2_bf = (u16*)alloc((size_t)NB * NF * 2);
  u16* hz_bf = (u16*)alloc((size_t)NB * NZ * 2);
  u16* hzp_bf = (u16*)alloc((size_t)NB * NZ * 2);
  u16* s_bf  = (u16*)alloc((size_t)NB * NH * 2);
  (void)ws_size; (void)in_sizes; (void)n_in; (void)out_size;

  // ---- output section pointers ----
  float* out_ys   = out;
  float* out_mean = out_ys + (size_t)NB * NT * NF;
  float* out_logv = out_mean + (size_t)NB * NT * NZ;
  float* out_zs   = out_logv + (size_t)NB * NT * NZ;
  float* out_zps  = out_zs + (size_t)NB * NT * NZ;
  float* out_it   = out_zps + (size_t)NB * NT * NZ;
  float* out_te   = out_it + (size_t)NB * NT;

  dim3 blk(256);

  hipMemsetAsync(zero_start, 0, zero_bytes, stream);

  // weight transpose+cast (once per call)
  transpose_cast<<<dim3(NDK / 32, NG4 / 32), blk, 0, stream>>>(Wk, WkT, NDK, NG4);
  transpose_cast<<<dim3(NH / 32, NG4 / 32), blk, 0, stream>>>(Wr, WrT, NH, NG4);
  transpose_cast<<<dim3(NH / 32, NF / 32), blk, 0, stream>>>(W1, W1T, NH, NF);
  transpose_cast<<<dim3(NF / 32, NF / 32), blk, 0, stream>>>(W2, W2T, NF, NF);
  transpose_cast<<<dim3(NF / 32, NF / 32), blk, 0, stream>>>(W3, W3T, NF, NF);
  transpose_cast<<<dim3(6144 / 32, NZ / 32), blk, 0, stream>>>(W4, W4T, 6144, NZ);
  transpose_cast<<<dim3(NZ / 32, NZ / 32), blk, 0, stream>>>(W5, W56T, NZ, NZ);
  transpose_cast<<<dim3(NZ / 32, NZ / 32), blk, 0, stream>>>(W6, W56T + (size_t)NZ * NZ, NZ, NZ);
  transpose_cast<<<dim3(5120 / 32, NZ / 32), blk, 0, stream>>>(W7, W7T, 5120, NZ);
  transpose_cast<<<dim3(NZ / 32, NZ / 32), blk, 0, stream>>>(W8, W89T, NZ, NZ);
  transpose_cast<<<dim3(NZ / 32, NZ / 32), blk, 0, stream>>>(W9, W89T + (size_t)NZ * NZ, NZ, NZ);
  cast_f32_bf16<<<dim3(NB * NH / 4 / 256), blk, 0, stream>>>(h_i, hi_bf, NB * NH);
  build_bias<<<dim3(4), blk, 0, stream>>>(b5, b6, b56, b8, b9, b89);
  time_k<<<dim3(NB * NT / 256), blk, 0, stream>>>(in_t, alpha, beta, base_, tw, lam, out_it, out_te);

  auto gemm = [&](std::initializer_list<SrcDesc> srcs, int N, const float* C0,
                  const float* bias, int relu,
                  float* of0, int os0, float* of1, int os1, int nsplit,
                  u16* ob, int osb) {
    GemmArgs a{};
    int i = 0;
    for (auto& s : srcs) a.src[i++] = s;
    a.nsrc = i; a.N = N; a.C0 = C0; a.bias = bias; a.relu = relu; a.nsplit = nsplit;
    a.outf0 = of0; a.os0 = os0; a.outf1 = of1; a.os1 = os1; a.outbf = ob; a.osb = osb;
    gemm_ms<<<dim3(NB / 64, N / 64), dim3(256), 0, stream>>>(a);
  };

  // h_i contributions (constant across steps)
  gemm({{hi_bf, WkT + 512, NDK, NH}}, NG4, nullptr, bl, 0, Gc, NG4, nullptr, 0, NG4, nullptr, 0);
  gemm({{hi_bf, W4T, 6144, NH}}, NZ, nullptr, b4, 0, H4c, NZ, nullptr, 0, NZ, nullptr, 0);
  gemm({{hi_bf, W7T, 5120, NH}}, NZ, nullptr, b7, 0, H7c, NZ, nullptr, 0, NZ, nullptr, 0);

  u16* yb[2] = {y0, y1alt};
  u16* zb[2] = {z0, z1};
  for (int t = 0; t < NT; ++t) {
    u16* yp = yb[t & 1];  u16* yc = yb[(t + 1) & 1];
    u16* zp = zb[t & 1];  u16* zc = zb[(t + 1) & 1];

    // gates = Gc + z_prev@Wk[0:512] + y_prev@Wk[2560:3584] + h@Wr
    gemm({{zp, WkT, NDK, NZ}, {yp, WkT + 2560, NDK, NF}, {hbf, WrT, NH, NH}},
         NG4, Gc, nullptr, 0, gates, NG4, nullptr, 0, NG4, nullptr, 0);
    cell_k<<<dim3(NB * NH / 256), blk, 0, stream>>>(gates, lam, t, c, s_bf, hbf);

    // y chain
    gemm({{hbf, W1T, NH, NH}}, NF, nullptr, b1, 1, nullptr, 0, nullptr, 0, NF, y1_bf, NF);
    gemm({{y1_bf, W2T, NF, NF}}, NF, nullptr, b2, 1, nullptr, 0, nullptr, 0, NF, y2_bf, NF);
    gemm({{y2_bf, W3T, NF, NF}}, NF, nullptr, b3, 1,
         out_ys + (size_t)t * NF, NT * NF, nullptr, 0, NF, yc, NF);

    // inference head
    gemm({{s_bf, W4T + 2048, 6144, NH}, {yc, W4T + 4096, 6144, NF}, {yp, W4T + 5120, 6144, NF}},
         NZ, H4c, nullptr, 1, nullptr, 0, nullptr, 0, NZ, hz_bf, NZ);
    gemm({{hz_bf, W56T, NZ, NZ}}, 1024, nullptr, b56, 1,
         out_mean + (size_t)t * NZ, NT * NZ, out_logv + (size_t)t * NZ, NT * NZ, NZ, nullptr, 0);
    z_k<<<dim3(NB * NZ / 256), blk, 0, stream>>>(out_mean, out_logv, ninf, t, out_zs, zc);

    // prior head
    gemm({{s_bf, W7T + 2048, 5120, NH}, {yp, W7T + 4096, 5120, NF}},
         NZ, H7c, nullptr, 1, nullptr, 0, nullptr, 0, NZ, hzp_bf, NZ);
    gemm({{hzp_bf, W89T, NZ, NZ}}, 1024, nullptr, b89, 1, mp, NZ, lp, NZ, NZ, nullptr, 0);
    zp_k<<<dim3(NB * NZ / 256), blk, 0, stream>>>(mp, lp, npri, t, out_zps);
  }
}

// Round 4
// 3934.286 us; speedup vs baseline: 1.0821x; 1.0821x over previous
//
#include <hip/hip_runtime.h>
#include <stdint.h>
#include <initializer_list>

typedef unsigned short u16;
typedef __bf16 bf16x8 __attribute__((ext_vector_type(8)));
typedef float f32x4 __attribute__((ext_vector_type(4)));

static constexpr int NB  = 256;   // batch
static constexpr int NH  = 2048;  // H
static constexpr int NF  = 1024;  // F
static constexpr int NZ  = 512;   // Z
static constexpr int NT  = 16;    // T
static constexpr int NTS = 32;    // TS
static constexpr int NG4 = 8192;  // 4*H

// ---------- helpers ----------
__device__ __forceinline__ u16 f2bf(float f) {
  union { float f; uint32_t u; } x; x.f = f;
  uint32_t r = x.u + 0x7fffu + ((x.u >> 16) & 1u);
  return (u16)(r >> 16);
}
__device__ __forceinline__ float sigm(float x) { return 1.f / (1.f + expf(-x)); }

__device__ __forceinline__ void gload16(const void* g, void* l) {
  __builtin_amdgcn_global_load_lds(
      (__attribute__((address_space(1))) void*)const_cast<void*>(g),
      (__attribute__((address_space(3))) void*)l, 16, 0, 0);
}

// ---------- weight transpose slice + cast: WT[n][k-k_lo] = bf16(W[k][n]) ----------
__global__ __launch_bounds__(256) void transpose_slice(const float* __restrict__ W,
                                                       u16* __restrict__ WT,
                                                       int N, int k_lo, int k_len) {
  __shared__ float tile[32][33];
  const int kk0 = blockIdx.x * 32;            // col offset in WT
  const int n0 = blockIdx.y * 32;
  const int t = threadIdx.x;
  const int r = t >> 3, cg = t & 7;
  const float4 v = *(const float4*)(W + (size_t)(k_lo + kk0 + r) * N + n0 + cg * 4);
  tile[r][cg * 4 + 0] = v.x; tile[r][cg * 4 + 1] = v.y;
  tile[r][cg * 4 + 2] = v.z; tile[r][cg * 4 + 3] = v.w;
  __syncthreads();
  ushort4 o;
  o.x = f2bf(tile[cg * 4 + 0][r]);
  o.y = f2bf(tile[cg * 4 + 1][r]);
  o.z = f2bf(tile[cg * 4 + 2][r]);
  o.w = f2bf(tile[cg * 4 + 3][r]);
  *(ushort4*)(WT + (size_t)(n0 + r) * k_len + kk0 + cg * 4) = o;
}

__global__ __launch_bounds__(256) void cast_f32_bf16(const float* __restrict__ src,
                                                     u16* __restrict__ dst, int n) {
  int i = (blockIdx.x * 256 + threadIdx.x) * 4;
  if (i < n) {
    float4 v = *(const float4*)(src + i);
    ushort4 o; o.x = f2bf(v.x); o.y = f2bf(v.y); o.z = f2bf(v.z); o.w = f2bf(v.w);
    *(ushort4*)(dst + i) = o;
  }
}

__global__ __launch_bounds__(256) void build_bias(const float* b5, const float* b6,
                                                  const float* b8, const float* b9,
                                                  float* bq) {
  int i = blockIdx.x * 256 + threadIdx.x;     // grid 8 -> 2048 threads
  if (i < 2048)
    bq[i] = (i < 512) ? b5[i] : (i < 1024) ? b6[i - 512] : (i < 1536) ? b8[i - 1024] : b9[i - 1536];
}

// ---------- time / lam precompute (fp32 exact) ----------
__global__ __launch_bounds__(256) void time_k(const float* __restrict__ input_t,
                                              const float* alpha, const float* beta,
                                              const float* base_, const float* tw,
                                              float* __restrict__ lam_buf,
                                              float* __restrict__ out_it,
                                              float* __restrict__ out_te) {
  int i = blockIdx.x * 256 + threadIdx.x;     // NB*NT
  int b = i >> 4, j = i & 15;
  const float* row = input_t + b * NTS;
  float cur = row[16 + j];
  float trig = 0.f;
  int lim = 16 + j;
  for (int s = 0; s < lim; ++s) trig += expf(row[s] - cur);
  float lam = base_[0] + alpha[0] * beta[0] * trig;
  float x = lam * (2048.f * tw[0]);
  float dt = (x > 15.f) ? x : log1pf(expf(x));
  lam_buf[b * NT + j] = lam;
  out_it[j * NB + b] = cur;
  out_te[j * NB + b] = cur + dt;
}

// ---------- LSTM cell: sums 2 partials + Gc ----------
__global__ __launch_bounds__(256) void cell_k(const float* __restrict__ P,
                                              const float* __restrict__ Gc,
                                              const float* __restrict__ lam, int t,
                                              float* __restrict__ c,
                                              u16* __restrict__ s_bf,
                                              u16* __restrict__ h_bf) {
  const int i = (blockIdx.x * 256 + threadIdx.x) * 4;   // over NB*NH
  const int b = i >> 11, n = i & 2047;
  const size_t o0 = (size_t)b * NG4 + n;
  const float* P1 = P + (size_t)NB * NG4;
  f32x4 ig = *(const f32x4*)(P + o0)        + *(const f32x4*)(P1 + o0)        + *(const f32x4*)(Gc + o0);
  f32x4 fg = *(const f32x4*)(P + o0 + 2048) + *(const f32x4*)(P1 + o0 + 2048) + *(const f32x4*)(Gc + o0 + 2048);
  f32x4 gg = *(const f32x4*)(P + o0 + 4096) + *(const f32x4*)(P1 + o0 + 4096) + *(const f32x4*)(Gc + o0 + 4096);
  f32x4 og = *(const f32x4*)(P + o0 + 6144) + *(const f32x4*)(P1 + o0 + 6144) + *(const f32x4*)(Gc + o0 + 6144);
  f32x4 cold = *(const f32x4*)(c + i);
  const float lm = lam[b * NT + t];
  f32x4 cout;
  ushort4 sv, hv;
  u16* sp = (u16*)&sv; u16* hp = (u16*)&hv;
#pragma unroll
  for (int r = 0; r < 4; ++r) {
    float cn = sigm(fg[r]) * cold[r] + sigm(ig[r]) * tanhf(gg[r]);
    float hn = sigm(og[r]) * tanhf(cn);
    cout[r] = lm * cn;
    sp[r] = f2bf(cn); hp[r] = f2bf(hn);
  }
  *(f32x4*)(c + i) = cout;
  *(ushort4*)(s_bf + i) = sv;
  *(ushort4*)(h_bf + i) = hv;
}

// ---------- z sampling (round-1-proven) ----------
__global__ __launch_bounds__(256) void z_k(const float* __restrict__ means,
                                           const float* __restrict__ logvs,
                                           const float* __restrict__ noise, int t,
                                           float* __restrict__ zs, u16* __restrict__ z_bf) {
  int i = blockIdx.x * 256 + threadIdx.x;       // NB*NZ
  int b = i >> 9, n = i & 511;
  size_t oidx = ((size_t)b * NT + t) * NZ + n;
  float zv = fmaf(noise[(size_t)t * NB * NZ + i], sqrtf(expf(logvs[oidx])), means[oidx]);
  zs[oidx] = zv;
  z_bf[i] = f2bf(zv);
}

__global__ __launch_bounds__(256) void zp_k(const float* __restrict__ mp,
                                            const float* __restrict__ lp,
                                            const float* __restrict__ noise, int t,
                                            float* __restrict__ zps) {
  int i = blockIdx.x * 256 + threadIdx.x;       // NB*NZ
  int b = i >> 9, n = i & 511;
  float zv = fmaf(noise[(size_t)t * NB * NZ + i], sqrtf(expf(lp[i])), mp[i]);
  zps[((size_t)b * NT + t) * NZ + n] = zv;
}

// ---------- combine: sum KS partials + C0 + bias, relu; n<nsplit -> *0 else *1 ----------
struct CArgs {
  const float* P; int KS, N, nsplit;
  const float* C0; const float* bias; int relu;
  float* of0; float* of1; int ofrs0, ofrs1;
  u16* ob0; u16* ob1; int obrs0, obrs1;
};
__global__ __launch_bounds__(256) void comb_k(CArgs a) {
  const int i = (blockIdx.x * 256 + threadIdx.x) * 4;
  const int MN = NB * a.N;
  if (i >= MN) return;
  const int m = i / a.N, n = i - m * a.N;
  f32x4 v = *(const f32x4*)(a.P + i);
  for (int j = 1; j < a.KS; ++j) v += *(const f32x4*)(a.P + (size_t)j * MN + i);
  if (a.C0)  v += *(const f32x4*)(a.C0 + i);
  if (a.bias) v += *(const f32x4*)(a.bias + n);
  if (a.relu) {
#pragma unroll
    for (int r = 0; r < 4; ++r) v[r] = fmaxf(v[r], 0.f);
  }
  float* of = a.of0; u16* ob = a.ob0;
  int nn = n, ofrs = a.ofrs0, obrs = a.obrs0;
  if (n >= a.nsplit) { of = a.of1; ob = a.ob1; nn = n - a.nsplit; ofrs = a.ofrs1; obrs = a.obrs1; }
  if (of) *(f32x4*)(of + (size_t)m * ofrs + nn) = v;
  if (ob) {
    ushort4 o; o.x = f2bf(v[0]); o.y = f2bf(v[1]); o.z = f2bf(v[2]); o.w = f2bf(v[3]);
    *(ushort4*)(ob + (size_t)m * obrs + nn) = o;
  }
}

// ---------- GEMM v2: M=256, N-tile=64, BK=32, depth-3 counted-vmcnt pipeline ----------
// C[m][n] = sum over chunk-matched sources of A_s[m][:] . W_s[n][:] (bf16 MFMA, fp32 acc)
struct Src { const u16* A; const u16* W; int lda, ldw, K, chunk; };
struct GArgs {
  Src s[4]; int ns, N, partial, relu, acg;
  float* P;                 // partial mode: P[bz][256][N]
  const float* bias;
  float* of; int of_rs;
  u16* ob; int ob_rs;
};

__global__ __launch_bounds__(256, 1) void gemm2(GArgs g) {
  __shared__ __attribute__((aligned(16))) char lds[3 * 20480];
  const int tid = threadIdx.x, lane = tid & 63, wave = tid >> 6;
  const int n0 = blockIdx.x * 64, bz = blockIdx.y;

  struct MS { const u16* A; const u16* W; int lda, ldw, iters; };
  MS ms[4]; int nms = 0, tot = 0;
  for (int i = 0; i < g.ns; ++i) {
    if (g.s[i].chunk == bz) {
      ms[nms].A = g.s[i].A;
      ms[nms].W = g.s[i].W + (size_t)n0 * g.s[i].ldw;
      ms[nms].lda = g.s[i].lda; ms[nms].ldw = g.s[i].ldw;
      ms[nms].iters = g.s[i].K >> 5;
      tot += ms[nms].iters; ++nms;
    }
  }

  const int srow = lane >> 2;                                  // 0..15
  const int schunk = (((lane & 3) ^ ((lane >> 3) & 3)) << 3);  // swizzled k-chunk (elems)
  auto STAGE = [&](int idx) {
    int rem = idx, si = 0;
    while (rem >= ms[si].iters) { rem -= ms[si].iters; ++si; }
    const int koff = (rem << 5) + schunk;
    char* base = lds + (idx % 3) * 20480;
    const u16* ga = ms[si].A + (size_t)(wave * 64 + srow) * ms[si].lda + koff;
    const size_t astep = (size_t)16 * ms[si].lda;
    char* ad = base + wave * 4096;
    gload16(ga, ad);
    gload16(ga + astep, ad + 1024);
    gload16(ga + 2 * astep, ad + 2048);
    gload16(ga + 3 * astep, ad + 3072);
    gload16(ms[si].W + (size_t)(wave * 16 + srow) * ms[si].ldw + koff,
            base + 16384 + wave * 1024);
  };

  int rA[4], rW[4];
  const int b15 = lane & 15, hi = lane >> 4, rx = (b15 >> 1) & 3;
#pragma unroll
  for (int f = 0; f < 4; ++f) rA[f] = (wave * 64 + f * 16 + b15) * 64 + ((hi ^ rx) << 4);
#pragma unroll
  for (int q = 0; q < 4; ++q) rW[q] = 16384 + (q * 16 + b15) * 64 + ((hi ^ rx) << 4);

  f32x4 acc[4][4] = {};
  const int npro = tot < 3 ? tot : 3;
  for (int j = 0; j < npro; ++j) STAGE(j);

  for (int i = 0; i < tot; ++i) {
    const int ahead = tot - 1 - i;
    if (ahead >= 2)      asm volatile("s_waitcnt vmcnt(10)" ::: "memory");
    else if (ahead == 1) asm volatile("s_waitcnt vmcnt(5)" ::: "memory");
    else                 asm volatile("s_waitcnt vmcnt(0)" ::: "memory");
    __builtin_amdgcn_sched_barrier(0);
    asm volatile("s_barrier" ::: "memory");       // tile i fully staged for ALL waves
    __builtin_amdgcn_sched_barrier(0);            // pin reads BELOW the barrier
    const char* base = lds + (i % 3) * 20480;
    bf16x8 av[4], bv[4];
#pragma unroll
    for (int f = 0; f < 4; ++f) av[f] = *(const bf16x8*)(base + rA[f]);
#pragma unroll
    for (int q = 0; q < 4; ++q) bv[q] = *(const bf16x8*)(base + rW[q]);
    asm volatile("s_waitcnt lgkmcnt(0)" ::: "memory");
    __builtin_amdgcn_sched_barrier(0);
    asm volatile("s_barrier" ::: "memory");       // all waves done reading buf (i%3)
    __builtin_amdgcn_sched_barrier(0);
    if (i + 3 < tot) STAGE(i + 3);                // refill the buffer just vacated
#pragma unroll
    for (int f = 0; f < 4; ++f)
#pragma unroll
      for (int q = 0; q < 4; ++q)
        acc[f][q] = __builtin_amdgcn_mfma_f32_16x16x32_bf16(av[f], bv[q], acc[f][q], 0, 0, 0);
  }

  if (g.partial) {
    float* P = g.P + (size_t)bz * NB * g.N;
#pragma unroll
    for (int f = 0; f < 4; ++f) {
      const int m = wave * 64 + f * 16 + hi * 4;
#pragma unroll
      for (int q = 0; q < 4; ++q) {
        const int n = n0 + q * 16 + b15;
#pragma unroll
        for (int r = 0; r < 4; ++r) P[(size_t)(m + r) * g.N + n] = acc[f][q][r];
      }
    }
  } else {
#pragma unroll
    for (int q = 0; q < 4; ++q) {
      const int n = n0 + q * 16 + b15;
      const float bb = g.bias ? g.bias[n] : 0.f;
#pragma unroll
      for (int f = 0; f < 4; ++f) {
        const int m = wave * 64 + f * 16 + hi * 4;
#pragma unroll
        for (int r = 0; r < 4; ++r) {
          float v = acc[f][q][r] + bb;
          if (g.acg) v += g.of[(size_t)(m + r) * g.of_rs + n];
          if (g.relu) v = fmaxf(v, 0.f);
          if (g.of) g.of[(size_t)(m + r) * g.of_rs + n] = v;
          if (g.ob) g.ob[(size_t)(m + r) * g.ob_rs + n] = f2bf(v);
        }
      }
    }
  }
}

// ---------- launcher ----------
extern "C" void kernel_launch(void* const* d_in, const int* in_sizes, int n_in,
                              void* d_out, int out_size, void* d_ws, size_t ws_size,
                              hipStream_t stream) {
  const float* h_i  = (const float*)d_in[0];
  const float* in_t = (const float*)d_in[1];
  const float* Wk   = (const float*)d_in[2];
  const float* Wr   = (const float*)d_in[3];
  const float* bl   = (const float*)d_in[4];
  const float* W1 = (const float*)d_in[5];  const float* b1 = (const float*)d_in[6];
  const float* W2 = (const float*)d_in[7];  const float* b2 = (const float*)d_in[8];
  const float* W3 = (const float*)d_in[9];  const float* b3 = (const float*)d_in[10];
  const float* W4 = (const float*)d_in[11]; const float* b4 = (const float*)d_in[12];
  const float* W5 = (const float*)d_in[13]; const float* b5 = (const float*)d_in[14];
  const float* W6 = (const float*)d_in[15]; const float* b6 = (const float*)d_in[16];
  const float* W7 = (const float*)d_in[17]; const float* b7 = (const float*)d_in[18];
  const float* W8 = (const float*)d_in[19]; const float* b8 = (const float*)d_in[20];
  const float* W9 = (const float*)d_in[21]; const float* b9 = (const float*)d_in[22];
  const float* alpha = (const float*)d_in[23];
  const float* beta  = (const float*)d_in[24];
  const float* base_ = (const float*)d_in[25];
  const float* tw    = (const float*)d_in[26];
  const float* ninf  = (const float*)d_in[27];
  const float* npri  = (const float*)d_in[28];
  float* out = (float*)d_out;
  (void)in_sizes; (void)n_in; (void)out_size; (void)ws_size;

  char* wsb = (char*)d_ws;
  size_t off = 0;
  auto alloc = [&](size_t bytes) -> void* {
    void* p = wsb + off;
    off += (bytes + 255) & ~(size_t)255;
    return p;
  };
  u16* WkzT = (u16*)alloc((size_t)NG4 * 512 * 2);    // Wk rows 0:512     -> [8192][512]
  u16* WkyT = (u16*)alloc((size_t)NG4 * 1024 * 2);   // Wk rows 2560:3584 -> [8192][1024]
  u16* WrT  = (u16*)alloc((size_t)NG4 * NH * 2);
  u16* W1T  = (u16*)alloc((size_t)NF * NH * 2);
  u16* W2T  = (u16*)alloc((size_t)NF * NF * 2);
  u16* W3T  = (u16*)alloc((size_t)NF * NF * 2);
  u16* W4T  = (u16*)alloc((size_t)NZ * 6144 * 2);
  u16* W56T = (u16*)alloc((size_t)1024 * NZ * 2);
  u16* W7T  = (u16*)alloc((size_t)NZ * 5120 * 2);
  u16* W89T = (u16*)alloc((size_t)1024 * NZ * 2);
  u16* hi_bf = (u16*)alloc((size_t)NB * NH * 2);
  float* bq  = (float*)alloc(2048 * 4);
  float* Gc  = (float*)alloc((size_t)NB * NG4 * 4);
  float* H4c = (float*)alloc((size_t)NB * NZ * 4);
  float* H7c = (float*)alloc((size_t)NB * NZ * 4);
  float* lam = (float*)alloc((size_t)NB * NT * 4);
  float* mp  = (float*)alloc((size_t)NB * NZ * 4);
  float* lp  = (float*)alloc((size_t)NB * NZ * 4);
  float* Pbuf = (float*)alloc((size_t)2 * NB * NG4 * 4);   // 16.8 MB, also midT scratch
  char* zero_start = wsb + off;
  u16* z0  = (u16*)alloc((size_t)NB * NZ * 2);
  u16* y0  = (u16*)alloc((size_t)NB * NF * 2);
  u16* hbf = (u16*)alloc((size_t)NB * NH * 2);
  float* c = (float*)alloc((size_t)NB * NH * 4);
  size_t zero_bytes = (size_t)((wsb + off) - zero_start);
  u16* y1alt = (u16*)alloc((size_t)NB * NF * 2);
  u16* y1_bf = (u16*)alloc((size_t)NB * NF * 2);
  u16* y2_bf = (u16*)alloc((size_t)NB * NF * 2);
  u16* hz_bf = (u16*)alloc((size_t)NB * NZ * 2);
  u16* hzp_bf = (u16*)alloc((size_t)NB * NZ * 2);
  u16* s_bf  = (u16*)alloc((size_t)NB * NH * 2);
  u16* midT = (u16*)Pbuf;                                   // [8192][1024] during setup

  // partial-buffer slices (all sequential uses, stream-ordered)
  float* PA  = Pbuf;                                // hz partials  [2][256][512]
  float* PB  = Pbuf + (size_t)2 * NB * 512;         // hzp partials [2][256][512]
  float* PQ1 = Pbuf + (size_t)4 * NB * 512;         // heads-inf    [2][256][1024]
  float* PQ2 = PQ1 + (size_t)2 * NB * 1024;         // heads-pri    [2][256][1024]

  float* out_ys   = out;
  float* out_mean = out_ys + (size_t)NB * NT * NF;
  float* out_logv = out_mean + (size_t)NB * NT * NZ;
  float* out_zs   = out_logv + (size_t)NB * NT * NZ;
  float* out_zps  = out_zs + (size_t)NB * NT * NZ;
  float* out_it   = out_zps + (size_t)NB * NT * NZ;
  float* out_te   = out_it + (size_t)NB * NT;

  dim3 blk(256);
  hipMemsetAsync(zero_start, 0, zero_bytes, stream);

  auto tr = [&](const float* W, u16* WT, int N, int k_lo, int k_len) {
    transpose_slice<<<dim3(k_len / 32, N / 32), blk, 0, stream>>>(W, WT, N, k_lo, k_len);
  };
  tr(Wk, WkzT, NG4, 0, 512);
  tr(Wk, WkyT, NG4, 2560, 1024);
  tr(Wr, WrT, NG4, 0, 2048);
  tr(W1, W1T, NF, 0, 2048);
  tr(W2, W2T, NF, 0, 1024);
  tr(W3, W3T, NF, 0, 1024);
  tr(W4, W4T, NZ, 0, 6144);
  tr(W5, W56T, NZ, 0, 512);
  tr(W6, W56T + (size_t)NZ * NZ, NZ, 0, 512);
  tr(W7, W7T, NZ, 0, 5120);
  tr(W8, W89T, NZ, 0, 512);
  tr(W9, W89T + (size_t)NZ * NZ, NZ, 0, 512);
  cast_f32_bf16<<<dim3(NB * NH / 4 / 256), blk, 0, stream>>>(h_i, hi_bf, NB * NH);
  build_bias<<<dim3(8), blk, 0, stream>>>(b5, b6, b8, b9, bq);
  time_k<<<dim3(NB * NT / 256), blk, 0, stream>>>(in_t, alpha, beta, base_, tw, lam, out_it, out_te);

  auto gemm = [&](std::initializer_list<Src> ss, int N, int KS, float* P,
                  const float* bias, int relu, int acg,
                  float* of, int of_rs, u16* ob, int ob_rs) {
    GArgs a{}; int i = 0;
    for (auto& s : ss) a.s[i++] = s;
    a.ns = i; a.N = N; a.partial = (P != nullptr); a.relu = relu; a.acg = acg;
    a.P = P; a.bias = bias; a.of = of; a.of_rs = of_rs; a.ob = ob; a.ob_rs = ob_rs;
    gemm2<<<dim3(N / 64, KS), dim3(256), 0, stream>>>(a);
  };
  auto comb = [&](CArgs a) {
    comb_k<<<dim3(NB * a.N / 4 / 256), blk, 0, stream>>>(a);
  };

  // Gc = h_i @ Wk[512:2560] + b_lstm, in two halves via midT scratch
  tr(Wk, midT, NG4, 512, 1024);
  gemm({{hi_bf, midT, 2048, 1024, 1024, 0}}, NG4, 1, nullptr, bl, 0, 0, Gc, NG4, nullptr, 0);
  tr(Wk, midT, NG4, 1536, 1024);
  gemm({{hi_bf + 1024, midT, 2048, 1024, 1024, 0}}, NG4, 1, nullptr, nullptr, 0, 1, Gc, NG4, nullptr, 0);
  // H4c = h_i @ W4[0:2048] + b4 ;  H7c = h_i @ W7[0:2048] + b7
  gemm({{hi_bf, W4T, 2048, 6144, 2048, 0}}, NZ, 1, nullptr, b4, 0, 0, H4c, NZ, nullptr, 0);
  gemm({{hi_bf, W7T, 2048, 5120, 2048, 0}}, NZ, 1, nullptr, b7, 0, 0, H7c, NZ, nullptr, 0);

  u16* yb[2] = {y0, y1alt};
  for (int t = 0; t < NT; ++t) {
    u16* yp = yb[t & 1];
    u16* yc = yb[(t + 1) & 1];

    // gates partials: chunk0 = z@Wkz + y@Wky, chunk1 = h@Wr
    gemm({{z0, WkzT, 512, 512, 512, 0},
          {yp, WkyT, 1024, 1024, 1024, 0},
          {hbf, WrT, 2048, 2048, 2048, 1}},
         NG4, 2, Pbuf, nullptr, 0, 0, nullptr, 0, nullptr, 0);
    cell_k<<<dim3(NB * NH / 4 / 256), blk, 0, stream>>>(Pbuf, Gc, lam, t, c, s_bf, hbf);

    // y-chain (KS=4 each)
    gemm({{hbf, W1T, 2048, 2048, 512, 0},
          {hbf + 512, W1T + 512, 2048, 2048, 512, 1},
          {hbf + 1024, W1T + 1024, 2048, 2048, 512, 2},
          {hbf + 1536, W1T + 1536, 2048, 2048, 512, 3}},
         NF, 4, Pbuf, nullptr, 0, 0, nullptr, 0, nullptr, 0);
    comb({Pbuf, 4, NF, NF, nullptr, b1, 1, nullptr, nullptr, 0, 0, y1_bf, nullptr, NF, 0});
    gemm({{y1_bf, W2T, 1024, 1024, 256, 0},
          {y1_bf + 256, W2T + 256, 1024, 1024, 256, 1},
          {y1_bf + 512, W2T + 512, 1024, 1024, 256, 2},
          {y1_bf + 768, W2T + 768, 1024, 1024, 256, 3}},
         NF, 4, Pbuf, nullptr, 0, 0, nullptr, 0, nullptr, 0);
    comb({Pbuf, 4, NF, NF, nullptr, b2, 1, nullptr, nullptr, 0, 0, y2_bf, nullptr, NF, 0});
    gemm({{y2_bf, W3T, 1024, 1024, 256, 0},
          {y2_bf + 256, W3T + 256, 1024, 1024, 256, 1},
          {y2_bf + 512, W3T + 512, 1024, 1024, 256, 2},
          {y2_bf + 768, W3T + 768, 1024, 1024, 256, 3}},
         NF, 4, Pbuf, nullptr, 0, 0, nullptr, 0, nullptr, 0);
    comb({Pbuf, 4, NF, NF, nullptr, b3, 1, out_ys + (size_t)t * NF, nullptr, NT * NF, 0, yc, nullptr, NF, 0});

    // hz = relu(H4c + s@W4[2048:4096] + yc@W4[4096:5120] + yp@W4[5120:6144])
    gemm({{s_bf, W4T + 2048, 2048, 6144, 2048, 0},
          {yc, W4T + 4096, 1024, 6144, 1024, 1},
          {yp, W4T + 5120, 1024, 6144, 1024, 1}},
         NZ, 2, PA, nullptr, 0, 0, nullptr, 0, nullptr, 0);
    comb({PA, 2, NZ, NZ, H4c, nullptr, 1, nullptr, nullptr, 0, 0, hz_bf, nullptr, NZ, 0});

    // hzp = relu(H7c + s@W7[2048:4096] + yp@W7[4096:5120])
    gemm({{s_bf, W7T + 2048, 2048, 5120, 2048, 0},
          {yp, W7T + 4096, 1024, 5120, 1024, 1}},
         NZ, 2, PB, nullptr, 0, 0, nullptr, 0, nullptr, 0);
    comb({PB, 2, NZ, NZ, H7c, nullptr, 1, nullptr, nullptr, 0, 0, hzp_bf, nullptr, NZ, 0});

    // heads-inf: [mean|logv] = relu(hz @ [W5|W6] + [b5|b6]), K=512 split 2x256
    gemm({{hz_bf, W56T, 512, 512, 256, 0},
          {hz_bf + 256, W56T + 256, 512, 512, 256, 1}},
         1024, 2, PQ1, nullptr, 0, 0, nullptr, 0, nullptr, 0);
    comb({PQ1, 2, 1024, 512, nullptr, bq, 1,
          out_mean + (size_t)t * NZ, out_logv + (size_t)t * NZ, NT * NZ, NT * NZ,
          nullptr, nullptr, 0, 0});
    // heads-pri: [mp|lp] = relu(hzp @ [W8|W9] + [b8|b9])
    gemm({{hzp_bf, W89T, 512, 512, 256, 0},
          {hzp_bf + 256, W89T + 256, 512, 512, 256, 1}},
         1024, 2, PQ2, nullptr, 0, 0, nullptr, 0, nullptr, 0);
    comb({PQ2, 2, 1024, 512, nullptr, bq + 1024, 1,
          mp, lp, NZ, NZ, nullptr, nullptr, 0, 0});

    z_k<<<dim3(NB * NZ / 256), blk, 0, stream>>>(out_mean, out_logv, ninf, t, out_zs, z0);
    zp_k<<<dim3(NB * NZ / 256), blk, 0, stream>>>(mp, lp, npri, t, out_zps);
  }
}